// Round 3
// baseline (498.107 us; speedup 1.0000x reference)
//
#include <hip/hip_runtime.h>
#include <hip/hip_bf16.h>

// Gumbel 2:4 masked linear:  out = x @ (W * mask)^T + bias
// Round 3: (a) prep split: LDS-free fully-linear cvt_x + standalone mask_w,
//          (b) GEMM switched to 32x32x16 bf16 MFMA (2382 vs 2075 TF ubench,
//              half the MFMA+ds_read instruction count per FLOP).

#define K_DIM 4096
#define N_DIM 4096
#define M_DIM 4096

typedef unsigned short ushort_t;
typedef __attribute__((ext_vector_type(8))) __bf16 bf16x8;
typedef __attribute__((ext_vector_type(16))) float floatx16;

__device__ __forceinline__ unsigned f2bf(float f) {
    union { float f; unsigned u; } v; v.f = f;
    unsigned u = v.u;
    return (u + 0x7fffu + ((u >> 16) & 1u)) >> 16;   // RNE
}

// patterns packed 4 bits each, idx0 at bits[3:0]: bit i = pattern[idx][i]
#define PAT_PACKED 0x3596ACu

// ---------------- x fp32 -> bf16, every access lane-consecutive ----------------
__global__ __launch_bounds__(256) void cvt_x_kernel(
    const float4* __restrict__ x4, uint2* __restrict__ o2) {
    const int base = blockIdx.x * 512 + threadIdx.x;   // 8192 blocks
    float4 a = x4[base], b = x4[base + 256];
    uint2 oa, ob;
    oa.x = f2bf(a.x) | (f2bf(a.y) << 16);
    oa.y = f2bf(a.z) | (f2bf(a.w) << 16);
    ob.x = f2bf(b.x) | (f2bf(b.y) << 16);
    ob.y = f2bf(b.z) | (f2bf(b.w) << 16);
    o2[base] = oa;
    o2[base + 256] = ob;
}

// ---------------- argmax mask + W fp32 -> masked bf16 ----------------
// per block: 1024 pattern-blocks; stage (gn+cw) into LDS via coalesced float4,
// argmax from LDS, mask W -> bf16. 4096 blocks.
__global__ __launch_bounds__(256) void mask_w_kernel(
    const float4* __restrict__ w4, const float4* __restrict__ cw4,
    const float4* __restrict__ gn4, uint2* __restrict__ wq2) {
    __shared__ float lsum[6144];                     // 1024 blocks x 6 logits
    const int tid = threadIdx.x;
    const int bb  = blockIdx.x;
    const float4* g4 = gn4 + (size_t)bb * 1536;
    const float4* c4 = cw4 + (size_t)bb * 1536;
    float4* l4 = (float4*)lsum;
#pragma unroll
    for (int j = 0; j < 6; j++) {                    // coalesced
        float4 g = g4[j * 256 + tid], c = c4[j * 256 + tid];
        float4 s;
        s.x = g.x + c.x; s.y = g.y + c.y; s.z = g.z + c.z; s.w = g.w + c.w;
        l4[j * 256 + tid] = s;
    }
    __syncthreads();

#pragma unroll
    for (int sub = 0; sub < 4; sub++) {
        const int pb = sub * 256 + tid;
        const float2* lp = (const float2*)&lsum[pb * 6];
        float2 v0 = lp[0], v1 = lp[1], v2 = lp[2];
        float v[6] = {v0.x, v0.y, v1.x, v1.y, v2.x, v2.y};
        int idx = 0; float m = v[0];
#pragma unroll
        for (int i = 1; i < 6; i++)                  // strict > : first-max (jnp.argmax)
            if (v[i] > m) { m = v[i]; idx = i; }
        const unsigned p = (PAT_PACKED >> (idx * 4)) & 0xF;
        const float4 w = w4[(size_t)bb * 1024 + pb];
        uint2 o;
        o.x = ((p & 1) ? f2bf(w.x) : 0u) | (((p >> 1) & 1) ? (f2bf(w.y) << 16) : 0u);
        o.y = (((p >> 2) & 1) ? f2bf(w.z) : 0u) | (((p >> 3) & 1) ? (f2bf(w.w) << 16) : 0u);
        wq2[(size_t)bb * 1024 + pb] = o;
    }
}

// ---------------- bf16 GEMM, C = A * B^T + bias ----------------
// 128x128 tile, BK=64, 256 thr (4 waves 2x2), per-wave 64x64 = 2x2 of 32x32x16.
// LDS As[row][chunk8] with physical chunk = c ^ (row&7) (XOR swizzle applied to
// the *global source* address since global_load_lds dest is lane-linear).
__device__ __forceinline__ void async16(const ushort_t* g, ushort_t* l) {
    __builtin_amdgcn_global_load_lds(
        (const __attribute__((address_space(1))) void*)g,
        (__attribute__((address_space(3))) void*)l, 16, 0, 0);
}

__global__ __launch_bounds__(256) void gemm_bt_kernel(
    const ushort_t* __restrict__ A,   // M x K bf16 (x)
    const ushort_t* __restrict__ B,   // N x K bf16 (masked W)
    const float* __restrict__ bias,
    float* __restrict__ C) {
    __shared__ ushort_t As[128 * 64];                // 16KB
    __shared__ ushort_t Bs[128 * 64];                // 16KB

    const int tid  = threadIdx.x;
    const int bm   = blockIdx.y * 128;
    const int bn   = blockIdx.x * 128;
    const int lane = tid & 63;
    const int wave = tid >> 6;
    const int wr   = (wave >> 1) * 64;
    const int wc   = (wave & 1) * 64;
    const int r32  = lane & 31;                      // fragment row (A.m / B.n / D.col)
    const int hi   = lane >> 5;                      // k-half within 16

    // staging: slot s = i*256+tid holds global chunk ((tid&7) ^ (row&7)) of row
    const int rA  = tid >> 3;
    const int swz = (tid & 7) ^ (rA & 7);
    const ushort_t* Ag = A + (size_t)(bm + rA) * K_DIM + swz * 8;
    const ushort_t* Bg = B + (size_t)(bn + rA) * K_DIM + swz * 8;
    ushort_t* lA = &As[tid * 8];
    ushort_t* lB = &Bs[tid * 8];

    floatx16 acc[2][2] = {};

    for (int kt = 0; kt < K_DIM; kt += 64) {
        __syncthreads();
#pragma unroll
        for (int i = 0; i < 4; i++) {
            async16(Ag + (size_t)i * 32 * K_DIM + kt, lA + i * 2048);
            async16(Bg + (size_t)i * 32 * K_DIM + kt, lB + i * 2048);
        }
        __syncthreads();

#pragma unroll
        for (int s = 0; s < 4; s++) {                // 4 k-steps of 16
            const int c = s * 2 + hi;                // k-chunk index [0,8)
            bf16x8 a[2], b[2];
#pragma unroll
            for (int rb = 0; rb < 2; rb++) {
                const int row = wr + rb * 32 + r32;
                a[rb] = *(const bf16x8*)&As[row * 64 + ((c ^ (row & 7)) * 8)];
            }
#pragma unroll
            for (int cb = 0; cb < 2; cb++) {
                const int row = wc + cb * 32 + r32;
                b[cb] = *(const bf16x8*)&Bs[row * 64 + ((c ^ (row & 7)) * 8)];
            }
#pragma unroll
            for (int rb = 0; rb < 2; rb++)
#pragma unroll
                for (int cb = 0; cb < 2; cb++)
                    acc[rb][cb] = __builtin_amdgcn_mfma_f32_32x32x16_bf16(
                        a[rb], b[cb], acc[rb][cb], 0, 0, 0);
        }
    }

    // epilogue: D col = lane&31, row = (reg&3) + 8*(reg>>2) + 4*hi
#pragma unroll
    for (int rb = 0; rb < 2; rb++) {
#pragma unroll
        for (int cb = 0; cb < 2; cb++) {
            const int gcol = bn + wc + cb * 32 + r32;
            const float bv = bias[gcol];
            const int rowbase = bm + wr + rb * 32 + 4 * hi;
#pragma unroll
            for (int reg = 0; reg < 16; reg++) {
                const int grow = rowbase + (reg & 3) + 8 * (reg >> 2);
                C[(size_t)grow * N_DIM + gcol] = acc[rb][cb][reg] + bv;
            }
        }
    }
}

extern "C" void kernel_launch(void* const* d_in, const int* in_sizes, int n_in,
                              void* d_out, int out_size, void* d_ws, size_t ws_size,
                              hipStream_t stream) {
    const float* x    = (const float*)d_in[0];
    const float* w    = (const float*)d_in[1];
    const float* bias = (const float*)d_in[2];
    const float* cw   = (const float*)d_in[3];
    const float* gn   = (const float*)d_in[4];
    ushort_t* xq = (ushort_t*)d_ws;                       // 32 MiB
    ushort_t* wq = xq + (size_t)M_DIM * K_DIM;            // 32 MiB
    float* out = (float*)d_out;

    cvt_x_kernel<<<8192, 256, 0, stream>>>((const float4*)x, (uint2*)xq);
    mask_w_kernel<<<4096, 256, 0, stream>>>((const float4*)w, (const float4*)cw,
                                            (const float4*)gn, (uint2*)wq);
    dim3 grid(N_DIM / 128, M_DIM / 128);
    gemm_bt_kernel<<<grid, 256, 0, stream>>>(xq, wq, bias, out);
}